// Round 1
// baseline (1655.281 us; speedup 1.0000x reference)
//
#include <hip/hip_runtime.h>
#include <math.h>

// Problem constants
#define B_SZ 256
#define N_SZ 100000
#define E_SZ 1280
#define D_SZ 512
#define K_SZ 8

// sims kernel tiling
#define BQ 128          // queries per block (grid.y = 2)
#define BJ 256          // index rows per block chunk
#define SUBJ 64         // sub-tile of j
#define KC 16           // k-slice staged in LDS
#define NCHUNKS ((N_SZ + BJ - 1) / BJ)   // 391

// top-8 streaming update; requires locals: bv[8], bi[8], minv, mins
#define TOP8_UPDATE(v_, i_)                                                 \
  if ((v_) > minv) {                                                        \
    _Pragma("unroll")                                                       \
    for (int s_ = 0; s_ < 8; ++s_)                                          \
      if (s_ == mins) { bv[s_] = (v_); bi[s_] = (i_); }                     \
    minv = bv[0]; mins = 0;                                                 \
    _Pragma("unroll")                                                       \
    for (int s_ = 1; s_ < 8; ++s_)                                          \
      if (bv[s_] < minv) { minv = bv[s_]; mins = s_; }                      \
  }

// ---------------- kernel 1: L2-normalize queries ----------------
__global__ __launch_bounds__(256) void k_normq(const float* __restrict__ q,
                                               float* __restrict__ qn) {
  __shared__ float red[4];
  int row = blockIdx.x, t = threadIdx.x;
  const float* src = q + (size_t)row * E_SZ;
  float x[5];
  float ss = 0.f;
#pragma unroll
  for (int i = 0; i < 5; ++i) { x[i] = src[t + 256 * i]; ss += x[i] * x[i]; }
#pragma unroll
  for (int o = 32; o > 0; o >>= 1) ss += __shfl_down(ss, o, 64);
  if ((t & 63) == 0) red[t >> 6] = ss;
  __syncthreads();
  float nrm = sqrtf(red[0] + red[1] + red[2] + red[3]);
  nrm = fmaxf(nrm, 1e-12f);
  float inv = 1.0f / nrm;
  float* dst = qn + (size_t)row * E_SZ;
#pragma unroll
  for (int i = 0; i < 5; ++i) dst[t + 256 * i] = x[i] * inv;
}

// ---------------- kernel 2: sims GEMM + fused per-chunk top-8 ----------------
// block: 256 threads = 16x16; tile 128q x 256j (4 sub-tiles of 64j), K=1280.
__global__ __launch_bounds__(256) void k_sims_topk(
    const float* __restrict__ qn, const float* __restrict__ emb,
    const int* __restrict__ excl, float* __restrict__ cval,
    int* __restrict__ cidx) {
  __shared__ float A[KC][132];  // [k][q], padded: conflict-free reads/writes
  __shared__ float Bt[KC][68];  // [k][j]
  __shared__ float S[BQ][68];   // sims sub-tile [q][j]

  int t = threadIdx.x;
  int tx = t & 15, ty = t >> 4;
  int qbase = blockIdx.y * BQ;
  int jchunk = blockIdx.x * BJ;

  float bv[8]; int bi[8];
#pragma unroll
  for (int s = 0; s < 8; ++s) { bv[s] = -1e30f; bi[s] = 0; }
  float minv = -1e30f; int mins = 0;
  int myexcl = (t < BQ) ? excl[qbase + t] : -1;

  for (int sub = 0; sub < BJ / SUBJ; ++sub) {
    int jbase = jchunk + sub * SUBJ;
    float acc[8][4];
#pragma unroll
    for (int i = 0; i < 8; ++i)
#pragma unroll
      for (int c = 0; c < 4; ++c) acc[i][c] = 0.f;

    for (int kt = 0; kt < E_SZ; kt += KC) {
      __syncthreads();
      // stage A (Q rows): 512 float4, 2 per thread, transposed into [k][q]
#pragma unroll
      for (int l = 0; l < 2; ++l) {
        int idx = t + 256 * l;
        int qq = idx >> 2;
        int ec = (idx & 3) * 4;
        const float4 v =
            *(const float4*)&qn[(size_t)(qbase + qq) * E_SZ + kt + ec];
        A[ec + 0][qq] = v.x; A[ec + 1][qq] = v.y;
        A[ec + 2][qq] = v.z; A[ec + 3][qq] = v.w;
      }
      // stage B (index rows): 256 float4, 1 per thread
      {
        int jj = t >> 2;
        int ec = (t & 3) * 4;
        int gj = jbase + jj;
        float4 v = make_float4(0.f, 0.f, 0.f, 0.f);
        if (gj < N_SZ) v = *(const float4*)&emb[(size_t)gj * E_SZ + kt + ec];
        Bt[ec + 0][jj] = v.x; Bt[ec + 1][jj] = v.y;
        Bt[ec + 2][jj] = v.z; Bt[ec + 3][jj] = v.w;
      }
      __syncthreads();
#pragma unroll
      for (int k = 0; k < KC; ++k) {
        float4 a0 = *(const float4*)&A[k][ty * 8];
        float4 a1 = *(const float4*)&A[k][ty * 8 + 4];
        float4 b  = *(const float4*)&Bt[k][tx * 4];
        float av[8] = {a0.x, a0.y, a0.z, a0.w, a1.x, a1.y, a1.z, a1.w};
        float bw[4] = {b.x, b.y, b.z, b.w};
#pragma unroll
        for (int i = 0; i < 8; ++i)
#pragma unroll
          for (int c = 0; c < 4; ++c)
            acc[i][c] = fmaf(av[i], bw[c], acc[i][c]);
      }
    }
    __syncthreads();
    // write sims sub-tile
#pragma unroll
    for (int i = 0; i < 8; ++i) {
      float4 v = make_float4(acc[i][0], acc[i][1], acc[i][2], acc[i][3]);
      *(float4*)&S[ty * 8 + i][tx * 4] = v;
    }
    __syncthreads();
    // per-query scan (threads 0..127 own one query row each)
    if (t < BQ) {
      for (int jj = 0; jj < SUBJ; ++jj) {
        int gj = jbase + jj;
        float v = S[t][jj];
        if (gj < N_SZ && gj != myexcl) { TOP8_UPDATE(v, gj); }
      }
    }
    // next sub-tile's first kt-loop barrier orders S reuse
  }
  if (t < BQ) {
    size_t base = ((size_t)(qbase + t) * NCHUNKS + blockIdx.x) * 8;
#pragma unroll
    for (int s = 0; s < 8; ++s) { cval[base + s] = bv[s]; cidx[base + s] = bi[s]; }
  }
}

// ---------------- kernel 3: merge per-chunk candidates -> global top-8 ----------------
__global__ __launch_bounds__(64) void k_merge(const float* __restrict__ cval,
                                              const int* __restrict__ cidx,
                                              int* __restrict__ topk) {
  __shared__ float sv[64 * 8];
  __shared__ int si[64 * 8];
  int q = blockIdx.x, t = threadIdx.x;
  float bv[8]; int bi[8];
#pragma unroll
  for (int s = 0; s < 8; ++s) { bv[s] = -1e30f; bi[s] = 0; }
  float minv = -1e30f; int mins = 0;
  for (int c = t; c < NCHUNKS; c += 64) {
    size_t base = ((size_t)q * NCHUNKS + c) * 8;
#pragma unroll
    for (int s = 0; s < 8; ++s) {
      float v = cval[base + s];
      int ix = cidx[base + s];
      TOP8_UPDATE(v, ix);
    }
  }
#pragma unroll
  for (int s = 0; s < 8; ++s) { sv[t * 8 + s] = bv[s]; si[t * 8 + s] = bi[s]; }
  __syncthreads();
  if (t == 0) {
#pragma unroll
    for (int s = 0; s < 8; ++s) { bv[s] = -1e30f; bi[s] = 0; }
    minv = -1e30f; mins = 0;
    for (int n = 0; n < 64 * 8; ++n) {
      float v = sv[n]; int ix = si[n];
      TOP8_UPDATE(v, ix);
    }
#pragma unroll
    for (int s = 0; s < 8; ++s) topk[q * 8 + s] = bi[s];
  }
}

// ---------------- kernel 4: gather neighbors + project (split-K partials) ----------------
#define PR 16    // rows per block
#define PKC 64   // e per LDS chunk
#define PES 320  // e per K-slice (grid.y = 4)
__global__ __launch_bounds__(256) void k_proj(const float* __restrict__ emb,
                                              const int* __restrict__ topk,
                                              const float* __restrict__ W,
                                              float* __restrict__ part) {
  __shared__ float A[PR][PKC];
  int t = threadIdx.x;
  int r0 = blockIdx.x * PR;
  int e0 = blockIdx.y * PES;
  int grow = topk[r0 + (t >> 4)];
  float acc0[PR], acc1[PR];
#pragma unroll
  for (int r = 0; r < PR; ++r) { acc0[r] = 0.f; acc1[r] = 0.f; }
  for (int ch = 0; ch < PES; ch += PKC) {
    __syncthreads();
    {
      int r = t >> 4, ec = (t & 15) * 4;
      float4 v = *(const float4*)&emb[(size_t)grow * E_SZ + e0 + ch + ec];
      *(float4*)&A[r][ec] = v;
    }
    __syncthreads();
    for (int e = 0; e < PKC; ++e) {
      float w0 = W[(size_t)(e0 + ch + e) * D_SZ + t];
      float w1 = W[(size_t)(e0 + ch + e) * D_SZ + t + 256];
#pragma unroll
      for (int r = 0; r < PR; ++r) {
        float a = A[r][e];
        acc0[r] = fmaf(a, w0, acc0[r]);
        acc1[r] = fmaf(a, w1, acc1[r]);
      }
    }
  }
  size_t pbase = (size_t)blockIdx.y * (2048u * 512u);
#pragma unroll
  for (int r = 0; r < PR; ++r) {
    part[pbase + (size_t)(r0 + r) * D_SZ + t] = acc0[r];
    part[pbase + (size_t)(r0 + r) * D_SZ + t + 256] = acc1[r];
  }
}

// ---------------- kernel 5: combine split-K partials + bias ----------------
__global__ __launch_bounds__(256) void k_combine(const float* __restrict__ part,
                                                 const float* __restrict__ bias,
                                                 float* __restrict__ out) {
  const size_t SL = 2048u * 512u;
  size_t i4 = (size_t)blockIdx.x * 256 + threadIdx.x;  // float4 id, 262144 total
  size_t off = i4 * 4;
  int d = (int)(off & 511);
  float4 a = *(const float4*)&part[off];
  float4 b = *(const float4*)&part[SL + off];
  float4 c = *(const float4*)&part[2 * SL + off];
  float4 e = *(const float4*)&part[3 * SL + off];
  float4 bb = *(const float4*)&bias[d];
  float4 r;
  r.x = a.x + b.x + c.x + e.x + bb.x;
  r.y = a.y + b.y + c.y + e.y + bb.y;
  r.z = a.z + b.z + c.z + e.z + bb.z;
  r.w = a.w + b.w + c.w + e.w + bb.w;
  *(float4*)&out[off] = r;
}

// ---------------- kernel 6: attention + logits + per-query loss partial ----------------
__global__ __launch_bounds__(256) void k_attn(
    const float* __restrict__ model, const float* __restrict__ proj,
    const int* __restrict__ topk, const int* __restrict__ labels,
    const float* __restrict__ clfW, const float* __restrict__ clfb,
    float* __restrict__ out, float* __restrict__ lossp) {
  __shared__ float P[8 * 512];
  __shared__ float red[4];
  int b = blockIdx.x, t = threadIdx.x;
  const float* src = proj + (size_t)b * 8 * 512;
#pragma unroll
  for (int i = 0; i < 4; ++i) {
    int o = i * 1024 + t * 4;
    *(float4*)&P[o] = *(const float4*)&src[o];
  }
  __syncthreads();
  float m0 = model[b * 512 + t], m1 = model[b * 512 + 256 + t];

  float sc[8];
#pragma unroll
  for (int k = 0; k < 8; ++k) {
    float p = m0 * P[k * 512 + t] + m1 * P[k * 512 + 256 + t];
#pragma unroll
    for (int o = 32; o > 0; o >>= 1) p += __shfl_down(p, o, 64);
    if ((t & 63) == 0) red[t >> 6] = p;
    __syncthreads();
    sc[k] = red[0] + red[1] + red[2] + red[3];
    __syncthreads();
  }
  const float scale = 0.04419417382415922f;  // 1/sqrt(512)
  float mx = -1e30f;
  float s_[8];
#pragma unroll
  for (int k = 0; k < 8; ++k) { s_[k] = sc[k] * scale; mx = fmaxf(mx, s_[k]); }
  float den = 0.f, att[8];
#pragma unroll
  for (int k = 0; k < 8; ++k) { att[k] = expf(s_[k] - mx); den += att[k]; }
  float iden = 1.0f / den;
#pragma unroll
  for (int k = 0; k < 8; ++k) att[k] *= iden;

  float z0 = 0.f, z1 = 0.f;
#pragma unroll
  for (int k = 0; k < 8; ++k) {
    z0 = fmaf(att[k], P[k * 512 + t], z0);
    z1 = fmaf(att[k], P[k * 512 + 256 + t], z1);
  }
  // logits: concat(model, z) @ clfW + clfb
#pragma unroll
  for (int c = 0; c < 2; ++c) {
    float lp = m0 * clfW[t * 2 + c] + m1 * clfW[(t + 256) * 2 + c] +
               z0 * clfW[(512 + t) * 2 + c] + z1 * clfW[(768 + t) * 2 + c];
#pragma unroll
    for (int o = 32; o > 0; o >>= 1) lp += __shfl_down(lp, o, 64);
    if ((t & 63) == 0) red[t >> 6] = lp;
    __syncthreads();
    if (t == 0) out[b * 2 + c] = red[0] + red[1] + red[2] + red[3] + clfb[c];
    __syncthreads();
  }
  // prototypes + loss partial
  float cp = 0.f, cn = 0.f;
  float p0 = 0.f, p1 = 0.f, n0 = 0.f, n1 = 0.f;
#pragma unroll
  for (int k = 0; k < 8; ++k) {
    int lb = labels[topk[b * 8 + k]];
    float mp = (lb == 1) ? 1.f : 0.f;
    float mn = (lb == 0) ? 1.f : 0.f;
    cp += mp; cn += mn;
    p0 = fmaf(mp, P[k * 512 + t], p0);
    p1 = fmaf(mp, P[k * 512 + 256 + t], p1);
    n0 = fmaf(mn, P[k * 512 + t], n0);
    n1 = fmaf(mn, P[k * 512 + 256 + t], n1);
  }
  float icp = 1.0f / (cp + 1e-6f), icn = 1.0f / (cn + 1e-6f);
  p0 *= icp; p1 *= icp; n0 *= icn; n1 *= icn;
  float lq = (m0 - p0) * (m0 - p0) + (m1 - p1) * (m1 - p1) -
             0.5f * ((m0 - n0) * (m0 - n0) + (m1 - n1) * (m1 - n1));
#pragma unroll
  for (int o = 32; o > 0; o >>= 1) lq += __shfl_down(lq, o, 64);
  if ((t & 63) == 0) red[t >> 6] = lq;
  __syncthreads();
  if (t == 0) lossp[b] = red[0] + red[1] + red[2] + red[3];
}

// ---------------- kernel 7: final loss reduction ----------------
__global__ __launch_bounds__(256) void k_loss(const float* __restrict__ lossp,
                                              float* __restrict__ out) {
  __shared__ float red[4];
  int t = threadIdx.x;
  float v = lossp[t];
#pragma unroll
  for (int o = 32; o > 0; o >>= 1) v += __shfl_down(v, o, 64);
  if ((t & 63) == 0) red[t >> 6] = v;
  __syncthreads();
  if (t == 0)
    out[512] = (red[0] + red[1] + red[2] + red[3]) * (1.0f / (256.0f * 512.0f));
}

extern "C" void kernel_launch(void* const* d_in, const int* in_sizes, int n_in,
                              void* d_out, int out_size, void* d_ws,
                              size_t ws_size, hipStream_t stream) {
  (void)in_sizes; (void)n_in; (void)out_size; (void)ws_size;
  const float* q      = (const float*)d_in[0];  // [256,1280]
  const float* model  = (const float*)d_in[1];  // [256,512]
  const float* emb    = (const float*)d_in[2];  // [100000,1280] (pre-normalized)
  const int*   labels = (const int*)d_in[3];    // [100000]
  const int*   excl   = (const int*)d_in[4];    // [256]
  const float* projW  = (const float*)d_in[5];  // [1280,512]
  const float* projb  = (const float*)d_in[6];  // [512]
  const float* clfW   = (const float*)d_in[7];  // [1024,2]
  const float* clfb   = (const float*)d_in[8];  // [2]
  float* out = (float*)d_out;                   // 512 logits + 1 loss

  // workspace layout (floats)
  float* ws    = (float*)d_ws;
  float* qn    = ws;                              // 327680
  float* cval  = qn + 327680;                     // 800768
  int*   cidx  = (int*)(cval + 800768);           // 800768
  int*   topk  = (int*)(cidx + 800768);           // 2048
  float* part  = (float*)(topk + 2048);           // 4*1048576
  float* nproj = part + 4 * 1048576;              // 1048576
  float* lossp = nproj + 1048576;                 // 256

  k_normq<<<256, 256, 0, stream>>>(q, qn);
  k_sims_topk<<<dim3(NCHUNKS, 2), 256, 0, stream>>>(qn, emb, excl, cval, cidx);
  k_merge<<<256, 64, 0, stream>>>(cval, cidx, topk);
  k_proj<<<dim3(128, 4), 256, 0, stream>>>(emb, topk, projW, part);
  k_combine<<<1024, 256, 0, stream>>>(part, projb, nproj);
  k_attn<<<256, 256, 0, stream>>>(model, nproj, topk, labels, clfW, clfb, out, lossp);
  k_loss<<<1, 256, 0, stream>>>(lossp, out);
}

// Round 2
// 486.753 us; speedup vs baseline: 3.4007x; 3.4007x over previous
//
#include <hip/hip_runtime.h>
#include <math.h>

// Problem constants
#define B_SZ 256
#define N_SZ 100000
#define E_SZ 1280
#define D_SZ 512

// sims kernel tiling (MFMA version)
#define JT 128                 // j rows per block
#define KSTEP 32               // K per MFMA step
#define NSTEP 40               // 1280/32
#define NCH 782                // ceil(100000/128)

typedef __attribute__((ext_vector_type(8))) short s8v;   // 8 bf16
typedef __attribute__((ext_vector_type(4))) float f32x4; // MFMA acc

__device__ __forceinline__ unsigned short f2bf(float f) {
  unsigned int u = __float_as_uint(f);
  u += 0x7fffu + ((u >> 16) & 1u);   // RNE
  return (unsigned short)(u >> 16);
}

// top-8 streaming update; requires locals: bv[8], bi[8], minv, mins
#define TOP8_UPDATE(v_, i_)                                                 \
  if ((v_) > minv) {                                                        \
    _Pragma("unroll")                                                       \
    for (int s_ = 0; s_ < 8; ++s_)                                          \
      if (s_ == mins) { bv[s_] = (v_); bi[s_] = (i_); }                     \
    minv = bv[0]; mins = 0;                                                 \
    _Pragma("unroll")                                                       \
    for (int s_ = 1; s_ < 8; ++s_)                                          \
      if (bv[s_] < minv) { minv = bv[s_]; mins = s_; }                      \
  }

// ---------------- kernel 1: L2-normalize queries -> bf16 ----------------
__global__ __launch_bounds__(256) void k_normq(const float* __restrict__ q,
                                               unsigned short* __restrict__ qn) {
  __shared__ float red[4];
  int row = blockIdx.x, t = threadIdx.x;
  const float* src = q + (size_t)row * E_SZ;
  float x[5];
  float ss = 0.f;
#pragma unroll
  for (int i = 0; i < 5; ++i) { x[i] = src[t + 256 * i]; ss += x[i] * x[i]; }
#pragma unroll
  for (int o = 32; o > 0; o >>= 1) ss += __shfl_down(ss, o, 64);
  if ((t & 63) == 0) red[t >> 6] = ss;
  __syncthreads();
  float nrm = sqrtf(red[0] + red[1] + red[2] + red[3]);
  nrm = fmaxf(nrm, 1e-12f);
  float inv = 1.0f / nrm;
  unsigned short* dst = qn + (size_t)row * E_SZ;
#pragma unroll
  for (int i = 0; i < 5; ++i) dst[t + 256 * i] = f2bf(x[i] * inv);
}

// ---------------- kernel 2: bf16 MFMA sims GEMM + fused per-chunk top-8 ----
// Block: 256 threads (4 waves). Tile: 256 q x 128 j, K = 1280 in 40 steps.
// Wave w owns rows [64w, 64w+64): acc[4 mq][8 nj] of 16x16 fragments.
// LDS chunk swizzle: 16B chunk c of row r stored at position c ^ swz(r&15),
// swz(r) = (r&3) ^ ((r>>2)&3)  -> fragment ds_read_b128 ~conflict-free.
__global__ __launch_bounds__(256) void k_sims_topk(
    const unsigned short* __restrict__ qn, const float* __restrict__ emb,
    const int* __restrict__ excl, float* __restrict__ cval,
    int* __restrict__ cidx) {
  __shared__ __align__(16) char lds[49408];
  // staging layout: A0 @0 (16KB), A1 @16384, B0 @32768 (8KB), B1 @40960
  // scan layout (after K-loop): S f32[64][129] @0, candV @33024, candI @41216

  const int t = threadIdx.x;
  const int l = t & 63, w = t >> 6;
  const int r15 = l & 15, g = l >> 4;
  const int ccol = ((g ^ ((r15 & 3) ^ ((r15 >> 2) & 3))) << 4);  // frag byte col
  const int jbase = blockIdx.x * JT;

  f32x4 acc[4][8];
#pragma unroll
  for (int mq = 0; mq < 4; ++mq)
#pragma unroll
    for (int nj = 0; nj < 8; ++nj) acc[mq][nj] = (f32x4)0.f;

  // --- staging assignments ---
  // A: thread t handles chunks ci = i*256 + t (i=0..3); row = ci>>2, x = ci&3
  // B: thread t handles rows t>>1, chunk positions bc0, bc0+1
  const int brow = t >> 1;
  const int bc0 = (t & 1) * 2;
  const int bsw = (brow & 3) ^ ((brow >> 2) & 3);
  const bool bvalid = (jbase + brow) < N_SZ;
  const float* bptr = emb + (size_t)(jbase + brow) * E_SZ;

  s8v areg[4];
  float4 breg[4];

#define A_LOAD(kt_)                                                          \
  {                                                                          \
    _Pragma("unroll") for (int i_ = 0; i_ < 4; ++i_) {                       \
      int ci_ = i_ * 256 + t;                                                \
      int row_ = ci_ >> 2, x_ = ci_ & 3;                                     \
      int sw_ = (row_ & 3) ^ ((row_ >> 2) & 3);                              \
      areg[i_] = *(const s8v*)(qn + (size_t)row_ * E_SZ + (kt_) +            \
                               ((x_ ^ sw_) << 3));                           \
    }                                                                        \
  }

#define A_WRITE(base_)                                                       \
  {                                                                          \
    _Pragma("unroll") for (int i_ = 0; i_ < 4; ++i_) {                       \
      *(s8v*)((base_) + (i_ * 256 + t) * 16) = areg[i_];                     \
    }                                                                        \
  }

#define B_LOAD(kt_)                                                          \
  {                                                                          \
    if (bvalid) {                                                            \
      int c0_ = bc0 ^ bsw, c1_ = (bc0 + 1) ^ bsw;                            \
      breg[0] = *(const float4*)(bptr + (kt_) + c0_ * 8);                    \
      breg[1] = *(const float4*)(bptr + (kt_) + c0_ * 8 + 4);                \
      breg[2] = *(const float4*)(bptr + (kt_) + c1_ * 8);                    \
      breg[3] = *(const float4*)(bptr + (kt_) + c1_ * 8 + 4);                \
    } else {                                                                 \
      breg[0] = breg[1] = breg[2] = breg[3] = make_float4(0.f, 0.f, 0.f, 0.f); \
    }                                                                        \
  }

#define B_WRITE(base_)                                                       \
  {                                                                          \
    uint4 p_;                                                                \
    p_.x = (unsigned)f2bf(breg[0].x) | ((unsigned)f2bf(breg[0].y) << 16);    \
    p_.y = (unsigned)f2bf(breg[0].z) | ((unsigned)f2bf(breg[0].w) << 16);    \
    p_.z = (unsigned)f2bf(breg[1].x) | ((unsigned)f2bf(breg[1].y) << 16);    \
    p_.w = (unsigned)f2bf(breg[1].z) | ((unsigned)f2bf(breg[1].w) << 16);    \
    *(uint4*)((base_) + brow * 64 + bc0 * 16) = p_;                          \
    p_.x = (unsigned)f2bf(breg[2].x) | ((unsigned)f2bf(breg[2].y) << 16);    \
    p_.y = (unsigned)f2bf(breg[2].z) | ((unsigned)f2bf(breg[2].w) << 16);    \
    p_.z = (unsigned)f2bf(breg[3].x) | ((unsigned)f2bf(breg[3].y) << 16);    \
    p_.w = (unsigned)f2bf(breg[3].z) | ((unsigned)f2bf(breg[3].w) << 16);    \
    *(uint4*)((base_) + brow * 64 + (bc0 + 1) * 16) = p_;                    \
  }

  // prologue: stage step 0 into buffer 0
  A_LOAD(0); B_LOAD(0);
  A_WRITE(lds); B_WRITE(lds + 32768);
  __syncthreads();

  for (int step = 0; step < NSTEP; ++step) {
    const int cur = step & 1;
    char* Ab = lds + cur * 16384;
    char* Bb = lds + 32768 + cur * 8192;
    char* An = lds + (cur ^ 1) * 16384;
    char* Bn = lds + 32768 + (cur ^ 1) * 8192;

    if (step + 1 < NSTEP) { A_LOAD((step + 1) * KSTEP); B_LOAD((step + 1) * KSTEP); }

    s8v af[4];
#pragma unroll
    for (int mq = 0; mq < 4; ++mq)
      af[mq] = *(const s8v*)(Ab + ((64 * w + 16 * mq + r15) << 6) + ccol);
#pragma unroll
    for (int nj = 0; nj < 8; ++nj) {
      s8v bf = *(const s8v*)(Bb + ((16 * nj + r15) << 6) + ccol);
#pragma unroll
      for (int mq = 0; mq < 4; ++mq)
        acc[mq][nj] = __builtin_amdgcn_mfma_f32_16x16x32_bf16(af[mq], bf,
                                                              acc[mq][nj], 0, 0, 0);
    }

    if (step + 1 < NSTEP) { A_WRITE(An); B_WRITE(Bn); }
    __syncthreads();
  }

  // ---- fused top-8 scan: 4 phases, one wave's 64x128 tile at a time ----
  float* Sf = (float*)lds;             // [64][129]
  float* cV = (float*)(lds + 33024);   // [32][64]
  int*   cI = (int*)(lds + 41216);     // [32][64]
  const int srow = t & 63, ssl = t >> 6;

  for (int ph = 0; ph < 4; ++ph) {
    if (w == ph) {
#pragma unroll
      for (int mq = 0; mq < 4; ++mq)
#pragma unroll
        for (int nj = 0; nj < 8; ++nj) {
#pragma unroll
          for (int r = 0; r < 4; ++r)
            Sf[(16 * mq + 4 * g + r) * 129 + 16 * nj + r15] = acc[mq][nj][r];
        }
    }
    __syncthreads();
    {
      int q = ph * 64 + srow;
      int ex = excl[q];
      float bv[8]; int bi[8];
#pragma unroll
      for (int s = 0; s < 8; ++s) { bv[s] = -1e30f; bi[s] = 0; }
      float minv = -1e30f; int mins = 0;
      for (int i = 0; i < 32; ++i) {
        int col = ssl * 32 + i;
        int gj = jbase + col;
        float v = Sf[srow * 129 + col];
        if (gj < N_SZ && gj != ex) { TOP8_UPDATE(v, gj); }
      }
#pragma unroll
      for (int s = 0; s < 8; ++s) {
        cV[(ssl * 8 + s) * 64 + srow] = bv[s];
        cI[(ssl * 8 + s) * 64 + srow] = bi[s];
      }
    }
    __syncthreads();
    if (t < 64) {
      float bv[8]; int bi[8];
#pragma unroll
      for (int s = 0; s < 8; ++s) { bv[s] = -1e30f; bi[s] = 0; }
      float minv = -1e30f; int mins = 0;
      for (int n = 0; n < 32; ++n) {
        float v = cV[n * 64 + t]; int ix = cI[n * 64 + t];
        TOP8_UPDATE(v, ix);
      }
      size_t base = ((size_t)(ph * 64 + t) * NCH + blockIdx.x) * 8;
#pragma unroll
      for (int s = 0; s < 8; ++s) { cval[base + s] = bv[s]; cidx[base + s] = bi[s]; }
    }
    __syncthreads();
  }
#undef A_LOAD
#undef A_WRITE
#undef B_LOAD
#undef B_WRITE
}

// ---------------- kernel 3: merge per-chunk candidates -> global top-8 ----------------
__global__ __launch_bounds__(64) void k_merge(const float* __restrict__ cval,
                                              const int* __restrict__ cidx,
                                              int* __restrict__ topk) {
  __shared__ float sv[64 * 8];
  __shared__ int si[64 * 8];
  int q = blockIdx.x, t = threadIdx.x;
  float bv[8]; int bi[8];
#pragma unroll
  for (int s = 0; s < 8; ++s) { bv[s] = -1e30f; bi[s] = 0; }
  float minv = -1e30f; int mins = 0;
  for (int c = t; c < NCH; c += 64) {
    size_t base = ((size_t)q * NCH + c) * 8;
#pragma unroll
    for (int s = 0; s < 8; ++s) {
      float v = cval[base + s];
      int ix = cidx[base + s];
      TOP8_UPDATE(v, ix);
    }
  }
#pragma unroll
  for (int s = 0; s < 8; ++s) { sv[t * 8 + s] = bv[s]; si[t * 8 + s] = bi[s]; }
  __syncthreads();
  if (t == 0) {
#pragma unroll
    for (int s = 0; s < 8; ++s) { bv[s] = -1e30f; bi[s] = 0; }
    minv = -1e30f; mins = 0;
    for (int n = 0; n < 64 * 8; ++n) {
      float v = sv[n]; int ix = si[n];
      TOP8_UPDATE(v, ix);
    }
#pragma unroll
    for (int s = 0; s < 8; ++s) topk[q * 8 + s] = bi[s];
  }
}

// ---------------- kernel 4: gather neighbors + project (split-K partials) ----------------
#define PR 16    // rows per block
#define PKC 64   // e per LDS chunk
#define PES 320  // e per K-slice (grid.y = 4)
__global__ __launch_bounds__(256) void k_proj(const float* __restrict__ emb,
                                              const int* __restrict__ topk,
                                              const float* __restrict__ W,
                                              float* __restrict__ part) {
  __shared__ float A[PR][PKC];
  int t = threadIdx.x;
  int r0 = blockIdx.x * PR;
  int e0 = blockIdx.y * PES;
  int grow = topk[r0 + (t >> 4)];
  float acc0[PR], acc1[PR];
#pragma unroll
  for (int r = 0; r < PR; ++r) { acc0[r] = 0.f; acc1[r] = 0.f; }
  for (int ch = 0; ch < PES; ch += PKC) {
    __syncthreads();
    {
      int r = t >> 4, ec = (t & 15) * 4;
      float4 v = *(const float4*)&emb[(size_t)grow * E_SZ + e0 + ch + ec];
      *(float4*)&A[r][ec] = v;
    }
    __syncthreads();
    for (int e = 0; e < PKC; ++e) {
      float w0 = W[(size_t)(e0 + ch + e) * D_SZ + t];
      float w1 = W[(size_t)(e0 + ch + e) * D_SZ + t + 256];
#pragma unroll
      for (int r = 0; r < PR; ++r) {
        float a = A[r][e];
        acc0[r] = fmaf(a, w0, acc0[r]);
        acc1[r] = fmaf(a, w1, acc1[r]);
      }
    }
  }
  size_t pbase = (size_t)blockIdx.y * (2048u * 512u);
#pragma unroll
  for (int r = 0; r < PR; ++r) {
    part[pbase + (size_t)(r0 + r) * D_SZ + t] = acc0[r];
    part[pbase + (size_t)(r0 + r) * D_SZ + t + 256] = acc1[r];
  }
}

// ---------------- kernel 5: combine split-K partials + bias ----------------
__global__ __launch_bounds__(256) void k_combine(const float* __restrict__ part,
                                                 const float* __restrict__ bias,
                                                 float* __restrict__ out) {
  const size_t SL = 2048u * 512u;
  size_t i4 = (size_t)blockIdx.x * 256 + threadIdx.x;
  size_t off = i4 * 4;
  int d = (int)(off & 511);
  float4 a = *(const float4*)&part[off];
  float4 b = *(const float4*)&part[SL + off];
  float4 c = *(const float4*)&part[2 * SL + off];
  float4 e = *(const float4*)&part[3 * SL + off];
  float4 bb = *(const float4*)&bias[d];
  float4 r;
  r.x = a.x + b.x + c.x + e.x + bb.x;
  r.y = a.y + b.y + c.y + e.y + bb.y;
  r.z = a.z + b.z + c.z + e.z + bb.z;
  r.w = a.w + b.w + c.w + e.w + bb.w;
  *(float4*)&out[off] = r;
}

// ---------------- kernel 6: attention + logits + per-query loss partial ----------------
__global__ __launch_bounds__(256) void k_attn(
    const float* __restrict__ model, const float* __restrict__ proj,
    const int* __restrict__ topk, const int* __restrict__ labels,
    const float* __restrict__ clfW, const float* __restrict__ clfb,
    float* __restrict__ out, float* __restrict__ lossp) {
  __shared__ float P[8 * 512];
  __shared__ float red[4];
  int b = blockIdx.x, t = threadIdx.x;
  const float* src = proj + (size_t)b * 8 * 512;
#pragma unroll
  for (int i = 0; i < 4; ++i) {
    int o = i * 1024 + t * 4;
    *(float4*)&P[o] = *(const float4*)&src[o];
  }
  __syncthreads();
  float m0 = model[b * 512 + t], m1 = model[b * 512 + 256 + t];

  float sc[8];
#pragma unroll
  for (int k = 0; k < 8; ++k) {
    float p = m0 * P[k * 512 + t] + m1 * P[k * 512 + 256 + t];
#pragma unroll
    for (int o = 32; o > 0; o >>= 1) p += __shfl_down(p, o, 64);
    if ((t & 63) == 0) red[t >> 6] = p;
    __syncthreads();
    sc[k] = red[0] + red[1] + red[2] + red[3];
    __syncthreads();
  }
  const float scale = 0.04419417382415922f;  // 1/sqrt(512)
  float mx = -1e30f;
  float s_[8];
#pragma unroll
  for (int k = 0; k < 8; ++k) { s_[k] = sc[k] * scale; mx = fmaxf(mx, s_[k]); }
  float den = 0.f, att[8];
#pragma unroll
  for (int k = 0; k < 8; ++k) { att[k] = expf(s_[k] - mx); den += att[k]; }
  float iden = 1.0f / den;
#pragma unroll
  for (int k = 0; k < 8; ++k) att[k] *= iden;

  float z0 = 0.f, z1 = 0.f;
#pragma unroll
  for (int k = 0; k < 8; ++k) {
    z0 = fmaf(att[k], P[k * 512 + t], z0);
    z1 = fmaf(att[k], P[k * 512 + 256 + t], z1);
  }
#pragma unroll
  for (int c = 0; c < 2; ++c) {
    float lp = m0 * clfW[t * 2 + c] + m1 * clfW[(t + 256) * 2 + c] +
               z0 * clfW[(512 + t) * 2 + c] + z1 * clfW[(768 + t) * 2 + c];
#pragma unroll
    for (int o = 32; o > 0; o >>= 1) lp += __shfl_down(lp, o, 64);
    if ((t & 63) == 0) red[t >> 6] = lp;
    __syncthreads();
    if (t == 0) out[b * 2 + c] = red[0] + red[1] + red[2] + red[3] + clfb[c];
    __syncthreads();
  }
  float cp = 0.f, cn = 0.f;
  float p0 = 0.f, p1 = 0.f, n0 = 0.f, n1 = 0.f;
#pragma unroll
  for (int k = 0; k < 8; ++k) {
    int lb = labels[topk[b * 8 + k]];
    float mp = (lb == 1) ? 1.f : 0.f;
    float mn = (lb == 0) ? 1.f : 0.f;
    cp += mp; cn += mn;
    p0 = fmaf(mp, P[k * 512 + t], p0);
    p1 = fmaf(mp, P[k * 512 + 256 + t], p1);
    n0 = fmaf(mn, P[k * 512 + t], n0);
    n1 = fmaf(mn, P[k * 512 + 256 + t], n1);
  }
  float icp = 1.0f / (cp + 1e-6f), icn = 1.0f / (cn + 1e-6f);
  p0 *= icp; p1 *= icp; n0 *= icn; n1 *= icn;
  float lq = (m0 - p0) * (m0 - p0) + (m1 - p1) * (m1 - p1) -
             0.5f * ((m0 - n0) * (m0 - n0) + (m1 - n1) * (m1 - n1));
#pragma unroll
  for (int o = 32; o > 0; o >>= 1) lq += __shfl_down(lq, o, 64);
  if ((t & 63) == 0) red[t >> 6] = lq;
  __syncthreads();
  if (t == 0) lossp[b] = red[0] + red[1] + red[2] + red[3];
}

// ---------------- kernel 7: final loss reduction ----------------
__global__ __launch_bounds__(256) void k_loss(const float* __restrict__ lossp,
                                              float* __restrict__ out) {
  __shared__ float red[4];
  int t = threadIdx.x;
  float v = lossp[t];
#pragma unroll
  for (int o = 32; o > 0; o >>= 1) v += __shfl_down(v, o, 64);
  if ((t & 63) == 0) red[t >> 6] = v;
  __syncthreads();
  if (t == 0)
    out[512] = (red[0] + red[1] + red[2] + red[3]) * (1.0f / (256.0f * 512.0f));
}

extern "C" void kernel_launch(void* const* d_in, const int* in_sizes, int n_in,
                              void* d_out, int out_size, void* d_ws,
                              size_t ws_size, hipStream_t stream) {
  (void)in_sizes; (void)n_in; (void)out_size; (void)ws_size;
  const float* q      = (const float*)d_in[0];  // [256,1280]
  const float* model  = (const float*)d_in[1];  // [256,512]
  const float* emb    = (const float*)d_in[2];  // [100000,1280]
  const int*   labels = (const int*)d_in[3];    // [100000]
  const int*   excl   = (const int*)d_in[4];    // [256]
  const float* projW  = (const float*)d_in[5];  // [1280,512]
  const float* projb  = (const float*)d_in[6];  // [512]
  const float* clfW   = (const float*)d_in[7];  // [1024,2]
  const float* clfb   = (const float*)d_in[8];  // [2]
  float* out = (float*)d_out;                   // 512 logits + 1 loss

  // workspace layout (bytes)
  char* ws = (char*)d_ws;
  unsigned short* qn = (unsigned short*)ws;            // 256*1280*2      = 655360
  float* cval = (float*)(ws + 655360);                 // 256*782*8*4     = 6406144
  int*   cidx = (int*)(ws + 7061504);                  // 6406144
  int*   topk = (int*)(ws + 13467648);                 // 8192
  float* part = (float*)(ws + 13475840);               // 4*2048*512*4    = 16777216
  float* nproj = part + 4 * 1048576;                   // 4194304
  float* lossp = nproj + 1048576;                      // 1024

  k_normq<<<256, 256, 0, stream>>>(q, qn);
  k_sims_topk<<<NCH, 256, 0, stream>>>(qn, emb, excl, cval, cidx);
  k_merge<<<256, 64, 0, stream>>>(cval, cidx, topk);
  k_proj<<<dim3(128, 4), 256, 0, stream>>>(emb, topk, projW, part);
  k_combine<<<1024, 256, 0, stream>>>(part, projb, nproj);
  k_attn<<<256, 256, 0, stream>>>(model, nproj, topk, labels, clfW, clfb, out, lossp);
  k_loss<<<1, 256, 0, stream>>>(lossp, out);
}

// Round 4
// 390.428 us; speedup vs baseline: 4.2397x; 1.2467x over previous
//
#include <hip/hip_runtime.h>
#include <math.h>

// Problem constants
#define B_SZ 256
#define N_SZ 100000
#define E_SZ 1280
#define D_SZ 512

#define NCH 1563   // ceil(100000 / 64) j-chunks

typedef __attribute__((ext_vector_type(8))) short s8v;   // 8 bf16
typedef __attribute__((ext_vector_type(4))) float f32x4; // MFMA acc

__device__ __forceinline__ unsigned short f2bf(float f) {
  unsigned int u = __float_as_uint(f);
  u += 0x7fffu + ((u >> 16) & 1u);   // RNE
  return (unsigned short)(u >> 16);
}
__device__ __forceinline__ unsigned int pack2(float a, float b) {
  return (unsigned)f2bf(a) | ((unsigned)f2bf(b) << 16);
}

// top-8 streaming update; requires locals: bv[8], bi[8], minv, mins
#define TOP8_UPDATE(v_, i_)                                                 \
  if ((v_) > minv) {                                                        \
    _Pragma("unroll")                                                       \
    for (int s_ = 0; s_ < 8; ++s_)                                          \
      if (s_ == mins) { bv[s_] = (v_); bi[s_] = (i_); }                     \
    minv = bv[0]; mins = 0;                                                 \
    _Pragma("unroll")                                                       \
    for (int s_ = 1; s_ < 8; ++s_)                                          \
      if (bv[s_] < minv) { minv = bv[s_]; mins = s_; }                      \
  }

// ---------------- kernel 1: L2-normalize queries -> bf16 ----------------
__global__ __launch_bounds__(256) void k_normq(const float* __restrict__ q,
                                               unsigned short* __restrict__ qn) {
  __shared__ float red[4];
  int row = blockIdx.x, t = threadIdx.x;
  const float* src = q + (size_t)row * E_SZ;
  float x[5];
  float ss = 0.f;
#pragma unroll
  for (int i = 0; i < 5; ++i) { x[i] = src[t + 256 * i]; ss += x[i] * x[i]; }
#pragma unroll
  for (int o = 32; o > 0; o >>= 1) ss += __shfl_down(ss, o, 64);
  if ((t & 63) == 0) red[t >> 6] = ss;
  __syncthreads();
  float nrm = sqrtf(red[0] + red[1] + red[2] + red[3]);
  nrm = fmaxf(nrm, 1e-12f);
  float inv = 1.0f / nrm;
  unsigned short* dst = qn + (size_t)row * E_SZ;
#pragma unroll
  for (int i = 0; i < 5; ++i) dst[t + 256 * i] = f2bf(x[i] * inv);
}

// ---------------- kernel 1b: transpose+convert projW -> Wt bf16 [512][1280] --
__global__ __launch_bounds__(256) void k_wt(const float* __restrict__ W,
                                            unsigned short* __restrict__ Wt) {
  __shared__ float T[64][65];
  const int kb = blockIdx.x * 64;   // 20 k-tiles
  const int nb = blockIdx.y * 64;   // 8 n-tiles
  const int t = threadIdx.x;
#pragma unroll
  for (int i = 0; i < 16; ++i) {
    int kr = i * 4 + (t >> 6);
    T[kr][t & 63] = W[(size_t)(kb + kr) * D_SZ + nb + (t & 63)];
  }
  __syncthreads();
  const int n = t >> 2, ks = (t & 3) * 16;
  unsigned int ow[8];
#pragma unroll
  for (int j = 0; j < 8; ++j)
    ow[j] = (unsigned)f2bf(T[ks + 2 * j][n]) |
            ((unsigned)f2bf(T[ks + 2 * j + 1][n]) << 16);
  unsigned short* dst = Wt + (size_t)(nb + n) * E_SZ + kb + ks;
  *(uint4*)dst = make_uint4(ow[0], ow[1], ow[2], ow[3]);
  *(uint4*)(dst + 8) = make_uint4(ow[4], ow[5], ow[6], ow[7]);
}

// ---------------- kernel 2: bf16 MFMA sims + fused per-chunk top-8 ----------
// 1563 blocks x 256 thr (4 waves). Tile 256q x 64j, K=1280 in 40 steps of 32.
// 2-deep register prefetch; raw s_barrier + lgkmcnt(0) only (loads stay in
// flight across barriers). Wave w owns q rows [64w,64w+64), all 64 j.
__global__ __launch_bounds__(256) void k_sims_topk(
    const unsigned short* __restrict__ qn, const float* __restrict__ emb,
    const int* __restrict__ excl, float* __restrict__ cval) {
  __shared__ __align__(16) char lds[40960];
  // A0 @0 (16K), A1 @16384, B0 @32768 (4K), B1 @36864
  const int t = threadIdx.x;
  const int l = t & 63, w = t >> 6;
  const int r15 = l & 15, g = l >> 4;
  const int jbase = blockIdx.x * 64;

  const int myq = (w << 6) + l;
  const int ex = excl[myq];

  f32x4 acc[4][4];
#pragma unroll
  for (int i = 0; i < 4; ++i)
#pragma unroll
    for (int j = 0; j < 4; ++j) acc[i][j] = (f32x4)0.f;

  const int ar = t >> 2;    // A rows: i*64 + ar
  const int akc = t & 3;
  const int brow = t >> 2;  // B row 0..63
  const int bkc = t & 3;
  const bool bval = (jbase + brow) < N_SZ;
  const float* bptr = emb + (size_t)(jbase + brow) * E_SZ + bkc * 8;

  char* A0 = lds;
  char* A1 = lds + 16384;
  char* B0 = lds + 32768;
  char* B1 = lds + 36864;

  int awoff[4];
#pragma unroll
  for (int i = 0; i < 4; ++i) {
    int row = i * 64 + ar;
    awoff[i] = row * 64 + (((akc + (row >> 1)) & 3) << 4);
  }
  const int bwoff = brow * 64 + (((bkc + (brow >> 1)) & 3) << 4);

  int afoff[4], bfoff[4];
#pragma unroll
  for (int mq = 0; mq < 4; ++mq) {
    int row = (w << 6) + 16 * mq + r15;
    afoff[mq] = row * 64 + (((g + (row >> 1)) & 3) << 4);
  }
#pragma unroll
  for (int nj = 0; nj < 4; ++nj) {
    int row = 16 * nj + r15;
    bfoff[nj] = row * 64 + (((g + (row >> 1)) & 3) << 4);
  }

  s8v a0[4], a1[4];
  float4 b0[2], b1[2];

#define LOADA(set_, kt_)                                                     \
  { _Pragma("unroll") for (int i_ = 0; i_ < 4; ++i_)                         \
      set_[i_] = *(const s8v*)(qn + (size_t)(i_ * 64 + ar) * E_SZ + (kt_) +  \
                               akc * 8); }
#define LOADB(set_, kt_)                                                     \
  { if (bval) { set_[0] = *(const float4*)(bptr + (kt_));                    \
                set_[1] = *(const float4*)(bptr + (kt_) + 4); }              \
    else { set_[0] = make_float4(0.f,0.f,0.f,0.f);                           \
           set_[1] = make_float4(0.f,0.f,0.f,0.f); } }
#define WRA(set_, base_)                                                     \
  { _Pragma("unroll") for (int i_ = 0; i_ < 4; ++i_)                         \
      *(s8v*)((base_) + awoff[i_]) = set_[i_]; }
#define WRB(set_, base_)                                                     \
  { uint4 p_;                                                                \
    p_.x = pack2(set_[0].x, set_[0].y); p_.y = pack2(set_[0].z, set_[0].w);  \
    p_.z = pack2(set_[1].x, set_[1].y); p_.w = pack2(set_[1].z, set_[1].w);  \
    *(uint4*)((base_) + bwoff) = p_; }
#define COMPUTE(Ab_, Bb_)                                                    \
  { s8v af_[4];                                                              \
    _Pragma("unroll") for (int mq_ = 0; mq_ < 4; ++mq_)                      \
      af_[mq_] = *(const s8v*)((Ab_) + afoff[mq_]);                          \
    _Pragma("unroll") for (int nj_ = 0; nj_ < 4; ++nj_) {                    \
      s8v bf_ = *(const s8v*)((Bb_) + bfoff[nj_]);                           \
      _Pragma("unroll") for (int mq_ = 0; mq_ < 4; ++mq_)                    \
        acc[mq_][nj_] = __builtin_amdgcn_mfma_f32_16x16x32_bf16(             \
            af_[mq_], bf_, acc[mq_][nj_], 0, 0, 0);                          \
    } }
#define FENCE_BAR                                                            \
  { asm volatile("s_waitcnt lgkmcnt(0)" ::: "memory");                       \
    __builtin_amdgcn_s_barrier(); }

  // prologue: step0 -> set0 -> buf0; step1 -> set1 (kept in regs)
  LOADA(a0, 0); LOADB(b0, 0);
  LOADA(a1, 32); LOADB(b1, 32);
  WRA(a0, A0); WRB(b0, B0);
  FENCE_BAR;

  for (int s = 0; s < 38; s += 2) {
    // even step s: prefetch s+2 -> set0; compute buf0; write set1(step s+1)->buf1
    LOADA(a0, (s + 2) * 32); LOADB(b0, (s + 2) * 32);
    COMPUTE(A0, B0);
    WRA(a1, A1); WRB(b1, B1);
    FENCE_BAR;
    // odd step s+1: prefetch s+3 -> set1; compute buf1; write set0(step s+2)->buf0
    LOADA(a1, (s + 3) * 32); LOADB(b1, (s + 3) * 32);
    COMPUTE(A1, B1);
    WRA(a0, A0); WRB(b0, B0);
    FENCE_BAR;
  }
  // step 38
  COMPUTE(A0, B0);
  WRA(a1, A1); WRB(b1, B1);
  FENCE_BAR;
  // step 39
  COMPUTE(A1, B1);
  FENCE_BAR;  // protect LDS overlay

  // ---- wave-local top-8 scan, 2 phases (waves {0,1} then {2,3}) ----
  float* Sbuf = (float*)(lds + (w & 1) * 16896);  // 64x66 f32
  for (int ph = 0; ph < 2; ++ph) {
    if ((w >> 1) == ph) {
#pragma unroll
      for (int mq = 0; mq < 4; ++mq)
#pragma unroll
        for (int nj = 0; nj < 4; ++nj)
#pragma unroll
          for (int r = 0; r < 4; ++r)
            Sbuf[(16 * mq + 4 * g + r) * 66 + 16 * nj + r15] = acc[mq][nj][r];
      float bv[8]; int bi[8];
#pragma unroll
      for (int s = 0; s < 8; ++s) { bv[s] = -1e30f; bi[s] = 0; }
      float minv = -1e30f; int mins = 0;
      const float* Srow = Sbuf + l * 66;
      for (int c = 0; c < 64; ++c) {
        int gj = jbase + c;
        float v = Srow[c];
        if (gj < N_SZ && gj != ex) { TOP8_UPDATE(v, gj); }
      }
      float* vdst = cval + (size_t)blockIdx.x * 4096 + myq * 8;
      *(float4*)vdst = make_float4(bv[0], bv[1], bv[2], bv[3]);
      *(float4*)(vdst + 4) = make_float4(bv[4], bv[5], bv[6], bv[7]);
      int* idst = (int*)(cval + (size_t)blockIdx.x * 4096 + 2048) + myq * 8;
      *(int4*)idst = make_int4(bi[0], bi[1], bi[2], bi[3]);
      *(int4*)(idst + 4) = make_int4(bi[4], bi[5], bi[6], bi[7]);
    }
    FENCE_BAR;
  }
#undef LOADA
#undef LOADB
#undef WRA
#undef WRB
#undef COMPUTE
#undef FENCE_BAR
}

// ---------------- kernel 3: merge per-chunk candidates -> global top-8 ------
__global__ __launch_bounds__(256) void k_merge(const float* __restrict__ cval,
                                               int* __restrict__ topk) {
  __shared__ float sv[2048];
  __shared__ int si[2048];
  const int q = blockIdx.x, t = threadIdx.x;
  float bv[8]; int bi[8];
#pragma unroll
  for (int s = 0; s < 8; ++s) { bv[s] = -1e30f; bi[s] = 0; }
  float minv = -1e30f; int mins = 0;
  for (int c = t; c < NCH; c += 256) {
    const float* vp = cval + (size_t)c * 4096 + q * 8;
    const int* ip = (const int*)(cval + (size_t)c * 4096 + 2048) + q * 8;
    float4 v0 = *(const float4*)vp, v1 = *(const float4*)(vp + 4);
    int4 i0 = *(const int4*)ip, i1 = *(const int4*)(ip + 4);
    float va[8] = {v0.x, v0.y, v0.z, v0.w, v1.x, v1.y, v1.z, v1.w};
    int ia[8] = {i0.x, i0.y, i0.z, i0.w, i1.x, i1.y, i1.z, i1.w};
#pragma unroll
    for (int s = 0; s < 8; ++s) {
      float v = va[s]; int ix = ia[s];
      TOP8_UPDATE(v, ix);
    }
  }
#pragma unroll
  for (int s = 0; s < 8; ++s) { sv[t * 8 + s] = bv[s]; si[t * 8 + s] = bi[s]; }
  __syncthreads();
  if (t < 64) {
    for (int rr = 1; rr < 4; ++rr) {
      int r = t + rr * 64;
#pragma unroll
      for (int s = 0; s < 8; ++s) {
        float v = sv[r * 8 + s]; int ix = si[r * 8 + s];
        TOP8_UPDATE(v, ix);
      }
    }
#pragma unroll
    for (int s = 0; s < 8; ++s) { sv[t * 8 + s] = bv[s]; si[t * 8 + s] = bi[s]; }
  }
  __syncthreads();
  if (t < 8) {
    for (int rr = 1; rr < 8; ++rr) {
      int r = t + rr * 8;
#pragma unroll
      for (int s = 0; s < 8; ++s) {
        float v = sv[r * 8 + s]; int ix = si[r * 8 + s];
        TOP8_UPDATE(v, ix);
      }
    }
#pragma unroll
    for (int s = 0; s < 8; ++s) { sv[t * 8 + s] = bv[s]; si[t * 8 + s] = bi[s]; }
  }
  __syncthreads();
  if (t == 0) {
    for (int r = 1; r < 8; ++r) {
#pragma unroll
      for (int s = 0; s < 8; ++s) {
        float v = sv[r * 8 + s]; int ix = si[r * 8 + s];
        TOP8_UPDATE(v, ix);
      }
    }
#pragma unroll
    for (int s = 0; s < 8; ++s) topk[q * 8 + s] = bi[s];
  }
}

// ---------------- kernel 4: gather + project via MFMA, bias fused -----------
// grid (16 Mtiles, 4 Ntiles), 256 thr (2x2 waves), tile 128x128, K=1280/64.
__global__ __launch_bounds__(256) void k_proj(
    const float* __restrict__ emb, const int* __restrict__ topk,
    const unsigned short* __restrict__ Wt, const float* __restrict__ bias,
    float* __restrict__ nproj) {
  __shared__ __align__(16) char lds[65536];  // A0 A1 B0 B1 each 16K
  const int t = threadIdx.x, l = t & 63, w = t >> 6;
  const int r15 = l & 15, g = l >> 4;
  const int wm = w >> 1, wn = w & 1;
  const int r0 = blockIdx.x * 128, n0 = blockIdx.y * 128;
  const int sr = t >> 3, kc = t & 7;

  int grow[4];
#pragma unroll
  for (int i = 0; i < 4; ++i) grow[i] = topk[r0 + i * 32 + sr];

  int woff[4];
#pragma unroll
  for (int i = 0; i < 4; ++i) {
    int row = i * 32 + sr;
    woff[i] = row * 128 + (((kc + (row & 7)) & 7) << 4);
  }
  int afoff[2][4], bfoff[2][4];
#pragma unroll
  for (int h = 0; h < 2; ++h) {
#pragma unroll
    for (int qq = 0; qq < 4; ++qq) {
      int rowa = 64 * wm + 16 * qq + r15;
      afoff[h][qq] = rowa * 128 + ((((h << 2) + g + (rowa & 7)) & 7) << 4);
      int rowb = 64 * wn + 16 * qq + r15;
      bfoff[h][qq] = rowb * 128 + ((((h << 2) + g + (rowb & 7)) & 7) << 4);
    }
  }

  f32x4 acc[4][4];
#pragma unroll
  for (int i = 0; i < 4; ++i)
#pragma unroll
    for (int j = 0; j < 4; ++j) acc[i][j] = (f32x4)0.f;

  float4 aset[4][2];
  s8v bset[4];

#define PLOADA(kt_)                                                          \
  { _Pragma("unroll") for (int i_ = 0; i_ < 4; ++i_) {                       \
      const float* s_ = emb + (size_t)grow[i_] * E_SZ + (kt_) + kc * 8;      \
      aset[i_][0] = *(const float4*)s_;                                      \
      aset[i_][1] = *(const float4*)(s_ + 4); } }
#define PLOADB(kt_)                                                          \
  { _Pragma("unroll") for (int i_ = 0; i_ < 4; ++i_)                         \
      bset[i_] = *(const s8v*)(Wt + (size_t)(n0 + i_ * 32 + sr) * E_SZ +     \
                               (kt_) + kc * 8); }
#define PWR(bA_, bB_)                                                        \
  { _Pragma("unroll") for (int i_ = 0; i_ < 4; ++i_) {                       \
      uint4 p_;                                                              \
      p_.x = pack2(aset[i_][0].x, aset[i_][0].y);                            \
      p_.y = pack2(aset[i_][0].z, aset[i_][0].w);                            \
      p_.z = pack2(aset[i_][1].x, aset[i_][1].y);                            \
      p_.w = pack2(aset[i_][1].z, aset[i_][1].w);                            \
      *(uint4*)((bA_) + woff[i_]) = p_;                                      \
      *(s8v*)((bB_) + woff[i_]) = bset[i_]; } }
#define PCOMP(bA_, bB_)                                                      \
  { _Pragma("unroll") for (int h_ = 0; h_ < 2; ++h_) {                       \
      s8v af_[4], bf_[4];                                                    \
      _Pragma("unroll") for (int q_ = 0; q_ < 4; ++q_) {                     \
        af_[q_] = *(const s8v*)((bA_) + afoff[h_][q_]);                      \
        bf_[q_] = *(const s8v*)((bB_) + bfoff[h_][q_]); }                    \
      _Pragma("unroll") for (int nj_ = 0; nj_ < 4; ++nj_)                    \
        _Pragma("unroll") for (int mq_ = 0; mq_ < 4; ++mq_)                  \
          acc[mq_][nj_] = __builtin_amdgcn_mfma_f32_16x16x32_bf16(           \
              af_[mq_], bf_[nj_], acc[mq_][nj_], 0, 0, 0); } }

  PLOADA(0); PLOADB(0);
  PWR(lds, lds + 32768);
  __syncthreads();
  for (int s = 0; s < 20; ++s) {
    char* cA = lds + (s & 1) * 16384;
    char* cB = lds + 32768 + (s & 1) * 16384;
    char* nA = lds + ((s + 1) & 1) * 16384;
    char* nB = lds + 32768 + ((s + 1) & 1) * 16384;
    if (s + 1 < 20) { PLOADA((s + 1) * 64); PLOADB((s + 1) * 64); }
    PCOMP(cA, cB);
    if (s + 1 < 20) { PWR(nA, nB); }
    __syncthreads();
  }
#pragma unroll
  for (int nj = 0; nj < 4; ++nj) {
    int n = n0 + 64 * wn + 16 * nj + r15;
    float bn = bias[n];
#pragma unroll
    for (int mq = 0; mq < 4; ++mq) {
      int m = r0 + 64 * wm + 16 * mq + 4 * g;
#pragma unroll
      for (int r = 0; r < 4; ++r)
        nproj[(size_t)(m + r) * D_SZ + n] = acc[mq][nj][r] + bn;
    }
  }
#undef PLOADA
#undef PLOADB
#undef PWR
#undef PCOMP
}

// ---------------- kernel 5: attention + logits + per-query loss partial -----
__global__ __launch_bounds__(256) void k_attn(
    const float* __restrict__ model, const float* __restrict__ proj,
    const int* __restrict__ topk, const int* __restrict__ labels,
    const float* __restrict__ clfW, const float* __restrict__ clfb,
    float* __restrict__ out, float* __restrict__ lossp) {
  __shared__ float P[8 * 512];
  __shared__ float red[4];
  int b = blockIdx.x, t = threadIdx.x;
  const float* src = proj + (size_t)b * 8 * 512;
#pragma unroll
  for (int i = 0; i < 4; ++i) {
    int o = i * 1024 + t * 4;
    *(float4*)&P[o] = *(const float4*)&src[o];
  }
  __syncthreads();
  float m0 = model[b * 512 + t], m1 = model[b * 512 + 256 + t];

  float sc[8];
#pragma unroll
  for (int k = 0; k < 8; ++k) {
    float p = m0 * P[k * 512 + t] + m1 * P[k * 512 + 256 + t];
#pragma unroll
    for (int o = 32; o > 0; o >>= 1) p += __shfl_down(p, o, 64);
    if ((t & 63) == 0) red[t >> 6] = p;
    __syncthreads();
    sc[k] = red[0] + red[1] + red[2] + red[3];
    __syncthreads();
  }
  const float scale = 0.04419417382415922f;  // 1/sqrt(512)
  float mx = -1e30f;
  float s_[8];
#pragma unroll
  for (int k = 0; k < 8; ++k) { s_[k] = sc[k] * scale; mx = fmaxf(mx, s_[k]); }
  float den = 0.f, att[8];
#pragma unroll
  for (int k = 0; k < 8; ++k) { att[k] = expf(s_[k] - mx); den += att[k]; }
  float iden = 1.0f / den;
#pragma unroll
  for (int k = 0; k < 8; ++k) att[k] *= iden;

  float z0 = 0.f, z1 = 0.f;
#pragma unroll
  for (int k = 0; k < 8; ++k) {
    z0 = fmaf(att[k], P[k * 512 + t], z0);
    z1 = fmaf(att[k], P[k * 512 + 256 + t], z1);
  }
#pragma unroll
  for (int c = 0; c < 2; ++c) {
    float lp = m0 * clfW[t * 2 + c] + m1 * clfW[(t + 256) * 2 + c] +
               z0 * clfW[(512 + t) * 2 + c] + z1 * clfW[(768 + t) * 2 + c];
#pragma unroll
    for (int o = 32; o > 0; o >>= 1) lp += __shfl_down(lp, o, 64);
    if ((t & 63) == 0) red[t >> 6] = lp;
    __syncthreads();
    if (t == 0) out[b * 2 + c] = red[0] + red[1] + red[2] + red[3] + clfb[c];
    __syncthreads();
  }
  float cp = 0.f, cn = 0.f;
  float p0 = 0.f, p1 = 0.f, n0 = 0.f, n1 = 0.f;
#pragma unroll
  for (int k = 0; k < 8; ++k) {
    int lb = labels[topk[b * 8 + k]];
    float mp = (lb == 1) ? 1.f : 0.f;
    float mn = (lb == 0) ? 1.f : 0.f;
    cp += mp; cn += mn;
    p0 = fmaf(mp, P[k * 512 + t], p0);
    p1 = fmaf(mp, P[k * 512 + 256 + t], p1);
    n0 = fmaf(mn, P[k * 512 + t], n0);
    n1 = fmaf(mn, P[k * 512 + 256 + t], n1);
  }
  float icp = 1.0f / (cp + 1e-6f), icn = 1.0f / (cn + 1e-6f);
  p0 *= icp; p1 *= icp; n0 *= icn; n1 *= icn;
  float lq = (m0 - p0) * (m0 - p0) + (m1 - p1) * (m1 - p1) -
             0.5f * ((m0 - n0) * (m0 - n0) + (m1 - n1) * (m1 - n1));
#pragma unroll
  for (int o = 32; o > 0; o >>= 1) lq += __shfl_down(lq, o, 64);
  if ((t & 63) == 0) red[t >> 6] = lq;
  __syncthreads();
  if (t == 0) lossp[b] = red[0] + red[1] + red[2] + red[3];
}

// ---------------- kernel 6: final loss reduction ----------------
__global__ __launch_bounds__(256) void k_loss(const float* __restrict__ lossp,
                                              float* __restrict__ out) {
  __shared__ float red[4];
  int t = threadIdx.x;
  float v = lossp[t];
#pragma unroll
  for (int o = 32; o > 0; o >>= 1) v += __shfl_down(v, o, 64);
  if ((t & 63) == 0) red[t >> 6] = v;
  __syncthreads();
  if (t == 0)
    out[512] = (red[0] + red[1] + red[2] + red[3]) * (1.0f / (256.0f * 512.0f));
}

extern "C" void kernel_launch(void* const* d_in, const int* in_sizes, int n_in,
                              void* d_out, int out_size, void* d_ws,
                              size_t ws_size, hipStream_t stream) {
  (void)in_sizes; (void)n_in; (void)out_size; (void)ws_size;
  const float* q      = (const float*)d_in[0];  // [256,1280]
  const float* model  = (const float*)d_in[1];  // [256,512]
  const float* emb    = (const float*)d_in[2];  // [100000,1280]
  const int*   labels = (const int*)d_in[3];    // [100000]
  const int*   excl   = (const int*)d_in[4];    // [256]
  const float* projW  = (const float*)d_in[5];  // [1280,512]
  const float* projb  = (const float*)d_in[6];  // [512]
  const float* clfW   = (const float*)d_in[7];  // [1024,2]
  const float* clfb   = (const float*)d_in[8];  // [2]
  float* out = (float*)d_out;                   // 512 logits + 1 loss

  // workspace layout (bytes)
  char* ws = (char*)d_ws;
  unsigned short* qn = (unsigned short*)ws;               // 655,360
  unsigned short* Wt = (unsigned short*)(ws + 655360);    // 1,310,720
  float* cval  = (float*)(ws + 1966080);                  // 1563*4096*4 = 25,608,192
  int*   topk  = (int*)(ws + 27574272);                   // 8,192
  float* nproj = (float*)(ws + 27582464);                 // 4,194,304
  float* lossp = (float*)(ws + 31776768);                 // 1,024

  k_normq<<<256, 256, 0, stream>>>(q, qn);
  k_wt<<<dim3(20, 8), 256, 0, stream>>>(projW, Wt);
  k_sims_topk<<<NCH, 256, 0, stream>>>(qn, emb, excl, cval);
  k_merge<<<256, 256, 0, stream>>>(cval, topk);
  k_proj<<<dim3(16, 4), 256, 0, stream>>>(emb, topk, Wt, projb, nproj);
  k_attn<<<256, 256, 0, stream>>>(model, nproj, topk, labels, clfW, clfb, out, lossp);
  k_loss<<<1, 256, 0, stream>>>(lossp, out);
}